// Round 1
// baseline (463.816 us; speedup 1.0000x reference)
//
#include <hip/hip_runtime.h>
#include <stdint.h>

#define N_ROWS 65536
#define NV 200
#define NH 128
#define NKD 32
#define NBKT 32768
#define NB2A 512  // blocks in k_main; 128 rows each

__device__ __forceinline__ uint32_t fkey(float x){
  uint32_t u = __float_as_uint(x);
  return (u & 0x80000000u) ? ~u : (u | 0x80000000u);
}

// ---------------- K0: extract tv/ti, tv histogram, tv partial stats ----------------
__global__ __launch_bounds__(256) void k_extract(
    const float* __restrict__ data, const int* __restrict__ tgt,
    float* __restrict__ tvArr, float* __restrict__ tiArr,
    unsigned int* __restrict__ histT, double* __restrict__ tvP){
  int i = blockIdx.x*256 + threadIdx.x;   // grid exactly N_ROWS threads
  int tg = *tgt;
  float v  = data[(size_t)i*600 + tg*3 + 0];
  float ti = data[(size_t)i*600 + tg*3 + 1];
  tvArr[i] = v; tiArr[i] = ti;
  atomicAdd(&histT[fkey(v)>>17], 1u);
  double s = (double)v, ss = (double)v*(double)v;
  float mn = v, mx = v;
  for (int off=32; off; off>>=1){
    s  += __shfl_down(s,  off);
    ss += __shfl_down(ss, off);
    mn = fminf(mn, __shfl_down(mn, off));
    mx = fmaxf(mx, __shfl_down(mx, off));
  }
  __shared__ double sd[4][4];
  int w = threadIdx.x >> 6;
  if ((threadIdx.x & 63) == 0){ sd[w][0]=s; sd[w][1]=ss; sd[w][2]=mn; sd[w][3]=mx; }
  __syncthreads();
  if (threadIdx.x == 0){
    double S=0, SS=0, MN=sd[0][2], MX=sd[0][3];
    for (int q=0;q<4;q++){ S+=sd[q][0]; SS+=sd[q][1]; MN=fmin(MN,sd[q][2]); MX=fmax(MX,sd[q][3]); }
    double* p = tvP + (size_t)blockIdx.x*4;
    p[0]=S; p[1]=SS; p[2]=MN; p[3]=MX;
  }
}

// ---------------- K0b: combine 256 tv partials ----------------
__global__ __launch_bounds__(256) void k_comb_tv(const double* __restrict__ tvP,
                                                 double* __restrict__ tvStats){
  int t = threadIdx.x;
  double s = tvP[t*4+0], ss = tvP[t*4+1], mn = tvP[t*4+2], mx = tvP[t*4+3];
  for (int off=32; off; off>>=1){
    s  += __shfl_down(s,  off);
    ss += __shfl_down(ss, off);
    mn = fmin(mn, __shfl_down(mn, off));
    mx = fmax(mx, __shfl_down(mx, off));
  }
  __shared__ double sd[4][4];
  int w = t >> 6;
  if ((t & 63) == 0){ sd[w][0]=s; sd[w][1]=ss; sd[w][2]=mn; sd[w][3]=mx; }
  __syncthreads();
  if (t == 0){
    double S=0, SS=0, MN=sd[0][2], MX=sd[0][3];
    for (int q=0;q<4;q++){ S+=sd[q][0]; SS+=sd[q][1]; MN=fmin(MN,sd[q][2]); MX=fmax(MX,sd[q][3]); }
    tvStats[0]=S; tvStats[1]=SS; tvStats[2]=MN; tvStats[3]=MX;
  }
}

// ---------------- K1s: scan tv histogram -> midrank LUT (f32 bits, in place) ----------------
__global__ __launch_bounds__(256) void k_scan(unsigned int* __restrict__ histT){
  int t = threadIdx.x;                 // 256 threads, 128 buckets each
  unsigned int s = 0;
  unsigned int loc[128];
  #pragma unroll 8
  for (int k=0;k<128;k++){ loc[k] = histT[t*128+k]; s += loc[k]; }
  __shared__ unsigned int aux[256];
  aux[t] = s; __syncthreads();
  for (int off=1; off<256; off<<=1){
    unsigned int v = (t>=off) ? aux[t-off] : 0u;
    __syncthreads();
    aux[t] += v;
    __syncthreads();
  }
  unsigned int run = aux[t] - s;       // exclusive prefix
  #pragma unroll 8
  for (int k=0;k<128;k++){
    unsigned int c = loc[k];
    float mid = (float)run + 0.5f*((float)c - 1.f);
    histT[t*128+k] = __float_as_uint(mid);
    run += c;
  }
}

// ---------------- K1b: tv midranks ----------------
__global__ __launch_bounds__(256) void k_trank(const float* __restrict__ tvArr,
                                               const unsigned int* __restrict__ histT,
                                               float* __restrict__ trArr){
  int i = blockIdx.x*256 + threadIdx.x;
  trArr[i] = __uint_as_float(histT[fkey(tvArr[i])>>17]);
}

// ---------------- K2a: main pass — per-column sums + min/max + bktT transpose ----------------
__global__ __launch_bounds__(256, 2) void k_main(
    const float* __restrict__ data, const float* __restrict__ tvArr,
    const float* __restrict__ tiArr, uint16_t* __restrict__ bktT,
    double* __restrict__ colP, float* __restrict__ colMM){
  __shared__ float   cvS[64][201];
  __shared__ uint8_t ciS[64][204];
  __shared__ float   tvS[66];
  __shared__ float   tiS[64];
  int t = threadIdx.x, blk = blockIdx.x;
  double acc[13];
  #pragma unroll
  for (int s=0;s<13;s++) acc[s]=0.0;
  float cmin = 3.4e38f, cmax = -3.4e38f;

  for (int st=0; st<2; ++st){
    int i0 = blk*128 + st*64;
    // ---- phase A: staged load, extract cv + ci into LDS ----
    const float4* rb = (const float4*)(data + (size_t)i0*600);
    #pragma unroll 2
    for (int k=0;k<38;k++){
      int f = t + k*256;
      if (f < 9600){
        float4 v = rb[f];
        int r  = f/150;
        int e4 = f - r*150;
        int m  = e4 % 3;
        int c0 = (4*e4)/3;
        if (m==0){ cvS[r][c0]=v.x; ciS[r][c0]=(uint8_t)(v.y>0.5f); cvS[r][c0+1]=v.w; }
        else if (m==1){ ciS[r][c0]=(uint8_t)(v.x>0.5f); cvS[r][c0+1]=v.z; ciS[r][c0+1]=(uint8_t)(v.w>0.5f); }
        else { cvS[r][c0+1]=v.y; ciS[r][c0+1]=(uint8_t)(v.z>0.5f); }
      }
    }
    if (t < 66){ int i = i0 - 1 + t; tvS[t] = (i>=0 && i<N_ROWS) ? tvArr[i] : 0.f; }
    else if (t >= 128 && t < 192){ tiS[t-128] = tiArr[i0 + (t-128)]; }
    __syncthreads();
    // ---- phase B: per-column accumulate (thread t <-> column t) ----
    if (t < NV){
      float facc[13];
      #pragma unroll
      for (int s=0;s<13;s++) facc[s]=0.f;
      for (int r=0;r<64;r++){
        float cv = cvS[r][t];
        float ci = (float)ciS[r][t];
        float tv = tvS[r+1], tvm = tvS[r], tvp = tvS[r+2];
        float ti = tiS[r];
        float b  = (1.f-ti)*(1.f-ci);
        facc[0]+=cv;        facc[1]+=cv*cv;     facc[2]+=tv*cv;
        facc[3]+=ci;        facc[4]+=tv*ci;
        facc[5]+=b;         facc[6]+=tv*b;      facc[7]+=cv*b;
        facc[8]+=tv*cv*b;   facc[9]+=tv*tv*b;   facc[10]+=cv*cv*b;
        facc[11]+=tvp*cv;   facc[12]+=tvm*cv;
        cmin = fminf(cmin, cv); cmax = fmaxf(cmax, cv);
      }
      #pragma unroll
      for (int s=0;s<13;s++) acc[s] += (double)facc[s];
    }
    // ---- phase C: transposed bucket write ----
    {
      int r = t & 63, cb = t >> 6;
      for (int cc=cb; cc<NV; cc+=4){
        float cv = cvS[r][cc];
        bktT[(size_t)cc*N_ROWS + i0 + r] = (uint16_t)(fkey(cv)>>17);
      }
    }
    __syncthreads();
  }
  if (t < NV){
    double* dst = colP + ((size_t)t*NB2A + blk)*16;
    #pragma unroll
    for (int s=0;s<13;s++) dst[s] = acc[s];
    float* mm = colMM + ((size_t)t*NB2A + blk)*2;
    mm[0]=cmin; mm[1]=cmax;
  }
}

// ---------------- K2c: combine per-column partials ----------------
__global__ __launch_bounds__(64) void k_comb_cols(const double* __restrict__ colP,
                                                  const float* __restrict__ colMM,
                                                  double* __restrict__ colStats){
  int j = blockIdx.x, t = threadIdx.x;     // 64 threads = 1 wave
  double a[13];
  #pragma unroll
  for (int s=0;s<13;s++) a[s]=0.0;
  float mn = 3.4e38f, mx = -3.4e38f;
  for (int b=t; b<NB2A; b+=64){
    const double* p = colP + ((size_t)j*NB2A + b)*16;
    #pragma unroll
    for (int s=0;s<13;s++) a[s] += p[s];
    const float* m = colMM + ((size_t)j*NB2A + b)*2;
    mn = fminf(mn, m[0]); mx = fmaxf(mx, m[1]);
  }
  for (int off=32; off; off>>=1){
    #pragma unroll
    for (int s=0;s<13;s++) a[s] += __shfl_down(a[s], off);
    mn = fminf(mn, __shfl_down(mn, off));
    mx = fmaxf(mx, __shfl_down(mx, off));
  }
  if (t == 0){
    double* d = colStats + (size_t)j*16;
    #pragma unroll
    for (int s=0;s<13;s++) d[s] = a[s];
    d[13] = (double)mn; d[14] = (double)mx;
  }
}

// ---------------- K2b: per-column Spearman numerator via LDS histogram midranks ----------------
__global__ __launch_bounds__(256) void k_rank(const uint16_t* __restrict__ bktT,
                                              const float* __restrict__ trArr,
                                              double* __restrict__ colStats){
  __shared__ unsigned int h[NBKT];     // 128 KB
  __shared__ unsigned int aux[256];
  __shared__ double daux[4];
  int t = threadIdx.x, j = blockIdx.x;
  const uint16_t* col = bktT + (size_t)j*N_ROWS;
  for (int k=t; k<NBKT; k+=256) h[k]=0u;
  __syncthreads();
  for (int k=0;k<N_ROWS/256;k++){
    int b = (int)col[t + k*256];
    atomicAdd(&h[b], 1u);
  }
  __syncthreads();
  unsigned int s = 0;
  for (int k=0;k<128;k++) s += h[t*128+k];
  aux[t]=s; __syncthreads();
  for (int off=1; off<256; off<<=1){
    unsigned int v = (t>=off) ? aux[t-off] : 0u;
    __syncthreads();
    aux[t] += v;
    __syncthreads();
  }
  unsigned int run = aux[t] - s;
  for (int k=0;k<128;k++){
    unsigned int c = h[t*128+k];
    float mid = (float)run + 0.5f*((float)c - 1.f);
    h[t*128+k] = __float_as_uint(mid);
    run += c;
  }
  __syncthreads();
  double srr = 0.0;
  for (int k=0;k<N_ROWS/256;k++){
    int i = t + k*256;
    int b = (int)col[i];
    srr += (double)trArr[i] * (double)__uint_as_float(h[b]);
  }
  for (int off=32; off; off>>=1) srr += __shfl_down(srr, off);
  if ((t&63)==0) daux[t>>6] = srr;
  __syncthreads();
  if (t==0) colStats[(size_t)j*16 + 15] = daux[0]+daux[1]+daux[2]+daux[3];
}

// ---------------- K5: features + attention/MLP head ----------------
__device__ __forceinline__ float gelu_t(float x){
  float x3 = x*x*x;
  return 0.5f*x*(1.f + tanhf(0.7978845608f*(x + 0.044715f*x3)));
}

__global__ __launch_bounds__(128) void k_head(
    const float* __restrict__ te, const float* __restrict__ ne, const float* __restrict__ data,
    const float* __restrict__ Wpair, const float* __restrict__ bpair,
    const float* __restrict__ Wq, const float* __restrict__ bq,
    const float* __restrict__ Wk, const float* __restrict__ bk,
    const float* __restrict__ W1, const float* __restrict__ b1,
    const float* __restrict__ lns, const float* __restrict__ lno,
    const float* __restrict__ W2, const float* __restrict__ b2,
    const float* __restrict__ W3, const float* __restrict__ b3,
    const float* __restrict__ Wd, const int* __restrict__ tgt,
    const double* __restrict__ colStats, const double* __restrict__ tvStats,
    const float* __restrict__ tvArr, float* __restrict__ out){
  int j = blockIdx.x, t = threadIdx.x;
  int tg = *tgt;
  // --- features (computed redundantly by every thread; all uniform loads) ---
  const double* cs = colStats + (size_t)j*16;
  double S_c=cs[0], S_cc=cs[1], S_tc=cs[2], S_ci=cs[3], S_ti=cs[4], S_b=cs[5],
         S_tb=cs[6], S_cb=cs[7], S_tcb=cs[8], S_ttb=cs[9], S_ccb=cs[10], L=cs[11], R=cs[12];
  float cmin=(float)cs[13], cmax=(float)cs[14];
  double S_rr=cs[15];
  double S_t=tvStats[0], S_tt=tvStats[1];
  float tmin=(float)tvStats[2], tmax=(float)tvStats[3];
  float tv0=tvArr[0], tvN=tvArr[N_ROWS-1];
  float cv0=data[j*3], cvN=data[(size_t)(N_ROWS-1)*600 + j*3];
  const double Nd = (double)N_ROWS;
  double n = S_b + 1e-8;
  double tmean=S_tb/n, cmean=S_cb/n;
  double cov=(S_tcb - tmean*S_cb - cmean*S_tb + tmean*cmean*S_b)/n;
  double t2=S_ttb - 2.0*tmean*S_tb + tmean*tmean*S_b;
  double c2=S_ccb - 2.0*cmean*S_cb + cmean*cmean*S_b;
  double tstd=sqrt(t2/n + 1e-8), cstd=sqrt(c2/n + 1e-8);
  double corr = cov/(tstd*cstd + 1e-8);
  double mi = -0.5*log(1.0 - fmin(corr*corr, 0.99) + 1e-8);
  float ovn = fminf(tmax,cmax) - fmaxf(tmin,cmin);
  float ovd = fmaxf(tmax-tmin, cmax-cmin) + 1e-8f;
  float overlap = fmaxf(0.f, ovn/ovd);
  double M = Nd - 1.0;
  double Sa=S_t-(double)tv0, Saa=S_tt-(double)tv0*(double)tv0;
  double Sb2=S_c-(double)cvN, Sbb=S_cc-(double)cvN*(double)cvN;
  double lnum = L - Sa*Sb2/M;
  double lden2 = (Saa - Sa*Sa/M)*(Sbb - Sb2*Sb2/M);
  double lag = (lden2 > 0.0) ? lnum/sqrt(lden2) : 0.0;
  double Sa2=S_t-(double)tvN, Saa2=S_tt-(double)tvN*(double)tvN;
  double Sc2=S_c-(double)cv0, Scc2=S_cc-(double)cv0*(double)cv0;
  double rnum = R - Sa2*Sc2/M;
  double rden2 = (Saa2 - Sa2*Sa2/M)*(Scc2 - Sc2*Sc2/M);
  double rev = (rden2 > 0.0) ? rnum/sqrt(rden2) : 0.0;
  double var_t = S_tt/Nd - (S_t/Nd)*(S_t/Nd);
  double var_c = S_cc/Nd - (S_c/Nd)*(S_c/Nd);
  double coef = corr*sqrt(var_t)/(sqrt(var_c) + 1e-8);
  double covf = S_tc/Nd - (S_t/Nd)*(S_c/Nd);
  double var_res = var_t + coef*coef*var_c - 2.0*coef*covf;
  double var_ratio = var_res/(var_t + 1e-8);
  double t_int = S_ti/(S_ci + 1e-8);
  double t_no  = (S_t - S_ti)/((Nd - S_ci) + 1e-8);
  double effect = fabs(t_int - t_no);
  const double m_ = (Nd-1.0)*0.5;
  double rank_corr = (S_rr - Nd*m_*m_) / (Nd*(Nd*Nd-1.0)/12.0);
  float pf[11];
  pf[0]=(float)corr; pf[1]=(float)fabs(corr); pf[2]=(float)(corr*corr); pf[3]=(float)mi;
  pf[4]=overlap; pf[5]=(float)effect; pf[6]=(float)rank_corr;
  pf[7]=(float)((corr>0.0)-(corr<0.0)); pf[8]=(float)lag; pf[9]=(float)rev; pf[10]=(float)var_ratio;
  if (j == tg){
    #pragma unroll
    for (int q=0;q<11;q++) pf[q]=0.f;
  }
  // --- MLP head ---
  const float* nej = ne + (size_t)j*NH;
  float h = b1[t];
  for (int e=0;e<NH;e++) h += te[e]*W1[e*NH + t];
  for (int e=0;e<NH;e++) h += nej[e]*W1[(NH+e)*NH + t];
  #pragma unroll
  for (int f=0;f<11;f++) h += 10.f*pf[f]*W1[(2*NH+f)*NH + t];
  h = gelu_t(h);
  __shared__ float redW[2];
  __shared__ float hnS[NH];
  __shared__ float h2S[64];
  float v = h;
  for (int off=32; off; off>>=1) v += __shfl_down(v, off);
  if ((t&63)==0) redW[t>>6]=v;
  __syncthreads();
  float mu = (redW[0]+redW[1])*(1.f/128.f);
  __syncthreads();
  float d = h - mu;
  v = d*d;
  for (int off=32; off; off>>=1) v += __shfl_down(v, off);
  if ((t&63)==0) redW[t>>6]=v;
  __syncthreads();
  float var = (redW[0]+redW[1])*(1.f/128.f);
  float hn = d/sqrtf(var + 1e-5f)*lns[t] + lno[t];
  hnS[t] = hn;
  __syncthreads();
  if (t < 64){
    float h2 = b2[t];
    for (int o=0;o<NH;o++) h2 += hnS[o]*W2[o*64 + t];
    h2S[t] = gelu_t(h2);
  }
  __syncthreads();
  float netv = 0.f, scv = 0.f;
  if (t < 64){
    float v2 = h2S[t]*W3[t];
    for (int off=32; off; off>>=1) v2 += __shfl_down(v2, off);
    if (t==0) netv = v2 + b3[0];
  }
  if (t < 32){
    float q = bq[t], k = bk[t] + bpair[t];
    for (int e=0;e<NH;e++){ q += te[e]*Wq[e*NKD + t]; k += nej[e]*Wk[e*NKD + t]; }
    #pragma unroll
    for (int f=0;f<11;f++) k += pf[f]*Wpair[f*NKD + t];
    float sc = k*q;
    for (int off=16; off; off>>=1) sc += __shfl_down(sc, off, 32);
    if (t==0) scv = sc/sqrtf(32.f);
  }
  if (t == 0){
    float direct = pf[0]*Wd[0] + pf[8]*Wd[1] + pf[10]*Wd[2];
    out[j] = scv + netv + 0.5f*direct;
  }
}

// ---------------- launcher ----------------
extern "C" void kernel_launch(void* const* d_in, const int* in_sizes, int n_in,
                              void* d_out, int out_size, void* d_ws, size_t ws_size,
                              hipStream_t stream) {
  const float* te    = (const float*)d_in[0];
  const float* ne    = (const float*)d_in[1];
  const float* data  = (const float*)d_in[2];
  const float* Wpair = (const float*)d_in[3];
  const float* bpair = (const float*)d_in[4];
  const float* Wq    = (const float*)d_in[5];
  const float* bq    = (const float*)d_in[6];
  const float* Wk    = (const float*)d_in[7];
  const float* bk    = (const float*)d_in[8];
  const float* W1    = (const float*)d_in[9];
  const float* b1    = (const float*)d_in[10];
  const float* lns   = (const float*)d_in[11];
  const float* lno   = (const float*)d_in[12];
  const float* W2    = (const float*)d_in[13];
  const float* b2    = (const float*)d_in[14];
  const float* W3    = (const float*)d_in[15];
  const float* b3    = (const float*)d_in[16];
  const float* Wd    = (const float*)d_in[17];
  const int*   tgt   = (const int*)d_in[18];
  float* out = (float*)d_out;

  char* ws = (char*)d_ws;
  size_t off = 0;
  auto alloc = [&](size_t bytes)->char*{
    char* p = ws + off;
    off = (off + bytes + 255) & ~(size_t)255;
    return p;
  };
  uint16_t*     bktT     = (uint16_t*)    alloc((size_t)NV*N_ROWS*2);
  float*        tvArr    = (float*)       alloc(N_ROWS*4);
  float*        tiArr    = (float*)       alloc(N_ROWS*4);
  float*        trArr    = (float*)       alloc(N_ROWS*4);
  unsigned int* histT    = (unsigned int*)alloc(NBKT*4);
  double*       tvP      = (double*)      alloc(256*4*8);
  double*       tvStats  = (double*)      alloc(4*8);
  double*       colP     = (double*)      alloc((size_t)NV*NB2A*16*8);
  float*        colMM    = (float*)       alloc((size_t)NV*NB2A*2*4);
  double*       colStats = (double*)      alloc((size_t)NV*16*8);
  if (off > ws_size) return;  // insufficient workspace -> fail visibly

  hipMemsetAsync(histT, 0, NBKT*4, stream);
  k_extract<<<dim3(N_ROWS/256), dim3(256), 0, stream>>>(data, tgt, tvArr, tiArr, histT, tvP);
  k_comb_tv<<<dim3(1), dim3(256), 0, stream>>>(tvP, tvStats);
  k_scan<<<dim3(1), dim3(256), 0, stream>>>(histT);
  k_trank<<<dim3(N_ROWS/256), dim3(256), 0, stream>>>(tvArr, histT, trArr);
  k_main<<<dim3(NB2A), dim3(256), 0, stream>>>(data, tvArr, tiArr, bktT, colP, colMM);
  k_comb_cols<<<dim3(NV), dim3(64), 0, stream>>>(colP, colMM, colStats);
  k_rank<<<dim3(NV), dim3(256), 0, stream>>>(bktT, trArr, colStats);
  k_head<<<dim3(NV), dim3(128), 0, stream>>>(te, ne, data, Wpair, bpair, Wq, bq, Wk, bk,
                                             W1, b1, lns, lno, W2, b2, W3, b3, Wd, tgt,
                                             colStats, tvStats, tvArr, out);
}

// Round 3
// 419.276 us; speedup vs baseline: 1.1062x; 1.1062x over previous
//
#include <hip/hip_runtime.h>
#include <stdint.h>

#define N_ROWS 65536
#define NV 200
#define NH 128
#define NKD 32
#define NBKT 32768
#define NB2A 512  // blocks in k_main; 128 rows each
#define ROWS_ST 32

__device__ __forceinline__ uint32_t fkey(float x){
  uint32_t u = __float_as_uint(x);
  return (u & 0x80000000u) ? ~u : (u | 0x80000000u);
}

// ---------------- K0: extract tv/ti, tv histogram, tv partial stats ----------------
__global__ __launch_bounds__(256) void k_extract(
    const float* __restrict__ data, const int* __restrict__ tgt,
    float* __restrict__ tvArr, float* __restrict__ tiArr,
    unsigned int* __restrict__ histT, double* __restrict__ tvP){
  int i = blockIdx.x*256 + threadIdx.x;   // grid exactly N_ROWS threads
  int tg = *tgt;
  float v  = data[(size_t)i*600 + tg*3 + 0];
  float ti = data[(size_t)i*600 + tg*3 + 1];
  tvArr[i] = v; tiArr[i] = ti;
  atomicAdd(&histT[fkey(v)>>17], 1u);
  double s = (double)v, ss = (double)v*(double)v;
  float mn = v, mx = v;
  for (int off=32; off; off>>=1){
    s  += __shfl_down(s,  off);
    ss += __shfl_down(ss, off);
    mn = fminf(mn, __shfl_down(mn, off));
    mx = fmaxf(mx, __shfl_down(mx, off));
  }
  __shared__ double sd[4][4];
  int w = threadIdx.x >> 6;
  if ((threadIdx.x & 63) == 0){ sd[w][0]=s; sd[w][1]=ss; sd[w][2]=mn; sd[w][3]=mx; }
  __syncthreads();
  if (threadIdx.x == 0){
    double S=0, SS=0, MN=sd[0][2], MX=sd[0][3];
    for (int q=0;q<4;q++){ S+=sd[q][0]; SS+=sd[q][1]; MN=fmin(MN,sd[q][2]); MX=fmax(MX,sd[q][3]); }
    double* p = tvP + (size_t)blockIdx.x*4;
    p[0]=S; p[1]=SS; p[2]=MN; p[3]=MX;
  }
}

// ---------------- K0b: combine 256 tv partials ----------------
__global__ __launch_bounds__(256) void k_comb_tv(const double* __restrict__ tvP,
                                                 double* __restrict__ tvStats){
  int t = threadIdx.x;
  double s = tvP[t*4+0], ss = tvP[t*4+1], mn = tvP[t*4+2], mx = tvP[t*4+3];
  for (int off=32; off; off>>=1){
    s  += __shfl_down(s,  off);
    ss += __shfl_down(ss, off);
    mn = fmin(mn, __shfl_down(mn, off));
    mx = fmax(mx, __shfl_down(mx, off));
  }
  __shared__ double sd[4][4];
  int w = t >> 6;
  if ((t & 63) == 0){ sd[w][0]=s; sd[w][1]=ss; sd[w][2]=mn; sd[w][3]=mx; }
  __syncthreads();
  if (t == 0){
    double S=0, SS=0, MN=sd[0][2], MX=sd[0][3];
    for (int q=0;q<4;q++){ S+=sd[q][0]; SS+=sd[q][1]; MN=fmin(MN,sd[q][2]); MX=fmax(MX,sd[q][3]); }
    tvStats[0]=S; tvStats[1]=SS; tvStats[2]=MN; tvStats[3]=MX;
  }
}

// ---------------- K1s: scan tv histogram -> midrank LUT (LDS, padded, conflict-free) ----------------
__global__ __launch_bounds__(256) void k_scan(unsigned int* __restrict__ histT){
  __shared__ unsigned int h[256*129];   // 132,096 B; chunk c at h[c*129 .. +127]
  __shared__ unsigned int aux[256];
  int t = threadIdx.x;
  for (int idx=t; idx<NBKT; idx+=256) h[(idx>>7)*129 + (idx&127)] = histT[idx];
  __syncthreads();
  unsigned int s = 0;
  #pragma unroll 8
  for (int k=0;k<128;k++) s += h[t*129+k];      // bank = (t+k)%32 : conflict-free
  aux[t] = s; __syncthreads();
  for (int off=1; off<256; off<<=1){
    unsigned int v = (t>=off) ? aux[t-off] : 0u;
    __syncthreads();
    aux[t] += v;
    __syncthreads();
  }
  unsigned int run = aux[t] - s;       // exclusive prefix of chunk
  #pragma unroll 8
  for (int k=0;k<128;k++){
    unsigned int c = h[t*129+k];
    h[t*129+k] = __float_as_uint((float)run + 0.5f*((float)c - 1.f));
    run += c;
  }
  __syncthreads();
  for (int idx=t; idx<NBKT; idx+=256) histT[idx] = h[(idx>>7)*129 + (idx&127)];
}

// ---------------- K1b: tv midranks ----------------
__global__ __launch_bounds__(256) void k_trank(const float* __restrict__ tvArr,
                                               const unsigned int* __restrict__ histT,
                                               float* __restrict__ trArr){
  int i = blockIdx.x*256 + threadIdx.x;
  trArr[i] = __uint_as_float(histT[fkey(tvArr[i])>>17]);
}

// ---------------- K2a: main pass — per-column sums + min/max + bktT transpose ----------------
__global__ __launch_bounds__(256, 4) void k_main(
    const float* __restrict__ data, const float* __restrict__ tvArr,
    const float* __restrict__ tiArr, uint16_t* __restrict__ bktT,
    float* __restrict__ colP){
  __shared__ float   cvS[ROWS_ST][201];
  __shared__ uint8_t ciS[ROWS_ST][204];
  __shared__ float   tvS[ROWS_ST+2];
  __shared__ float   tiS[ROWS_ST];
  int t = threadIdx.x, blk = blockIdx.x;
  double acc[13];
  #pragma unroll
  for (int s=0;s<13;s++) acc[s]=0.0;
  float cmin = 3.4e38f, cmax = -3.4e38f;

  for (int st=0; st<4; ++st){
    int i0 = blk*128 + st*ROWS_ST;
    // ---- phase A: staged load, extract cv + ci into LDS ----
    const float4* rb = (const float4*)(data + (size_t)i0*600);
    #pragma unroll 2
    for (int k=0;k<19;k++){
      int f = t + k*256;
      if (f < 4800){
        float4 v = rb[f];
        int r  = f/150;
        int e4 = f - r*150;
        int m  = e4 % 3;
        int c0 = (4*e4)/3;
        if (m==0){ cvS[r][c0]=v.x; ciS[r][c0]=(uint8_t)(v.y>0.5f); cvS[r][c0+1]=v.w; }
        else if (m==1){ ciS[r][c0]=(uint8_t)(v.x>0.5f); cvS[r][c0+1]=v.z; ciS[r][c0+1]=(uint8_t)(v.w>0.5f); }
        else { cvS[r][c0+1]=v.y; ciS[r][c0+1]=(uint8_t)(v.z>0.5f); }
      }
    }
    if (t < ROWS_ST+2){ int i = i0 - 1 + t; tvS[t] = (i>=0 && i<N_ROWS) ? tvArr[i] : 0.f; }
    else if (t >= 64 && t < 64+ROWS_ST){ tiS[t-64] = tiArr[i0 + (t-64)]; }
    __syncthreads();
    // ---- phase B: per-column accumulate (thread t <-> column t) ----
    if (t < NV){
      float facc[13];
      #pragma unroll
      for (int s=0;s<13;s++) facc[s]=0.f;
      for (int r=0;r<ROWS_ST;r++){
        float cv = cvS[r][t];
        float ci = (float)ciS[r][t];
        float tv = tvS[r+1], tvm = tvS[r], tvp = tvS[r+2];
        float ti = tiS[r];
        float b  = (1.f-ti)*(1.f-ci);
        facc[0]+=cv;        facc[1]+=cv*cv;     facc[2]+=tv*cv;
        facc[3]+=ci;        facc[4]+=tv*ci;
        facc[5]+=b;         facc[6]+=tv*b;      facc[7]+=cv*b;
        facc[8]+=tv*cv*b;   facc[9]+=tv*tv*b;   facc[10]+=cv*cv*b;
        facc[11]+=tvp*cv;   facc[12]+=tvm*cv;
        cmin = fminf(cmin, cv); cmax = fmaxf(cmax, cv);
      }
      #pragma unroll
      for (int s=0;s<13;s++) acc[s] += (double)facc[s];
    }
    // ---- phase C: transposed bucket write ----
    {
      int r = t & 31, cb = t >> 5;
      for (int cc=cb; cc<NV; cc+=8){
        float cv = cvS[r][cc];
        bktT[(size_t)cc*N_ROWS + i0 + r] = (uint16_t)(fkey(cv)>>17);
      }
    }
    __syncthreads();
  }
  if (t < NV){
    float* dst = colP + ((size_t)t*NB2A + blk)*16;
    #pragma unroll
    for (int s=0;s<13;s++) dst[s] = (float)acc[s];
    dst[13]=cmin; dst[14]=cmax;
  }
}

// ---------------- K2c: combine per-column partials ----------------
__global__ __launch_bounds__(256) void k_comb_cols(const float* __restrict__ colP,
                                                   double* __restrict__ colStats){
  int j = blockIdx.x, t = threadIdx.x;
  double a[13];
  #pragma unroll
  for (int s=0;s<13;s++) a[s]=0.0;
  float mn = 3.4e38f, mx = -3.4e38f;
  for (int b=t; b<NB2A; b+=256){
    const float* p = colP + ((size_t)j*NB2A + b)*16;
    #pragma unroll
    for (int s=0;s<13;s++) a[s] += (double)p[s];
    mn = fminf(mn, p[13]); mx = fmaxf(mx, p[14]);
  }
  for (int off=32; off; off>>=1){
    #pragma unroll
    for (int s=0;s<13;s++) a[s] += __shfl_down(a[s], off);
    mn = fminf(mn, __shfl_down(mn, off));
    mx = fmaxf(mx, __shfl_down(mx, off));
  }
  __shared__ double sd[4][15];
  int w = t >> 6;
  if ((t & 63) == 0){
    #pragma unroll
    for (int s=0;s<13;s++) sd[w][s]=a[s];
    sd[w][13]=(double)mn; sd[w][14]=(double)mx;
  }
  __syncthreads();
  if (t == 0){
    double* d = colStats + (size_t)j*16;
    #pragma unroll
    for (int s=0;s<13;s++) d[s] = sd[0][s]+sd[1][s]+sd[2][s]+sd[3][s];
    double MN=sd[0][13], MX=sd[0][14];
    for (int q=1;q<4;q++){ MN=fmin(MN,sd[q][13]); MX=fmax(MX,sd[q][14]); }
    d[13]=MN; d[14]=MX;
  }
}

// ---------------- K2b: per-column Spearman numerator via padded LDS histogram ----------------
__global__ __launch_bounds__(512, 1) void k_rank(const uint16_t* __restrict__ bktT,
                                                 const float* __restrict__ trArr,
                                                 double* __restrict__ colStats){
  __shared__ unsigned int h[512*65];   // 133,120 B; bucket b at h[(b>>6)*65 + (b&63)]
  __shared__ unsigned int aux[512];
  __shared__ double daux[8];
  int t = threadIdx.x, j = blockIdx.x;
  const uint16_t* col = bktT + (size_t)j*N_ROWS;
  for (int idx=t; idx<512*65; idx+=512) h[idx]=0u;
  __syncthreads();
  for (int k=0;k<N_ROWS/512;k++){
    int b = (int)col[t + k*512];
    atomicAdd(&h[(b>>6)*65 + (b&63)], 1u);
  }
  __syncthreads();
  unsigned int s = 0;
  #pragma unroll 8
  for (int k=0;k<64;k++) s += h[t*65+k];        // bank = (t+k)%32 : conflict-free
  aux[t]=s; __syncthreads();
  for (int off=1; off<512; off<<=1){
    unsigned int v = (t>=off) ? aux[t-off] : 0u;
    __syncthreads();
    aux[t] += v;
    __syncthreads();
  }
  unsigned int run = aux[t] - s;
  #pragma unroll 8
  for (int k=0;k<64;k++){
    unsigned int c = h[t*65+k];
    h[t*65+k] = __float_as_uint((float)run + 0.5f*((float)c - 1.f));
    run += c;
  }
  __syncthreads();
  double srr = 0.0;
  for (int k=0;k<N_ROWS/512;k++){
    int i = t + k*512;
    int b = (int)col[i];
    srr += (double)trArr[i] * (double)__uint_as_float(h[(b>>6)*65 + (b&63)]);
  }
  for (int off=32; off; off>>=1) srr += __shfl_down(srr, off);
  if ((t&63)==0) daux[t>>6] = srr;
  __syncthreads();
  if (t==0){
    double s8=0;
    for (int q=0;q<8;q++) s8 += daux[q];
    colStats[(size_t)j*16 + 15] = s8;
  }
}

// ---------------- K5: features + attention/MLP head ----------------
__device__ __forceinline__ float gelu_t(float x){
  float x3 = x*x*x;
  return 0.5f*x*(1.f + tanhf(0.7978845608f*(x + 0.044715f*x3)));
}

__global__ __launch_bounds__(128) void k_head(
    const float* __restrict__ te, const float* __restrict__ ne, const float* __restrict__ data,
    const float* __restrict__ Wpair, const float* __restrict__ bpair,
    const float* __restrict__ Wq, const float* __restrict__ bq,
    const float* __restrict__ Wk, const float* __restrict__ bk,
    const float* __restrict__ W1, const float* __restrict__ b1,
    const float* __restrict__ lns, const float* __restrict__ lno,
    const float* __restrict__ W2, const float* __restrict__ b2,
    const float* __restrict__ W3, const float* __restrict__ b3,
    const float* __restrict__ Wd, const int* __restrict__ tgt,
    const double* __restrict__ colStats, const double* __restrict__ tvStats,
    const float* __restrict__ tvArr, float* __restrict__ out){
  int j = blockIdx.x, t = threadIdx.x;
  int tg = *tgt;
  const double* cs = colStats + (size_t)j*16;
  double S_c=cs[0], S_cc=cs[1], S_tc=cs[2], S_ci=cs[3], S_ti=cs[4], S_b=cs[5],
         S_tb=cs[6], S_cb=cs[7], S_tcb=cs[8], S_ttb=cs[9], S_ccb=cs[10], L=cs[11], R=cs[12];
  float cmin=(float)cs[13], cmax=(float)cs[14];
  double S_rr=cs[15];
  double S_t=tvStats[0], S_tt=tvStats[1];
  float tmin=(float)tvStats[2], tmax=(float)tvStats[3];
  float tv0=tvArr[0], tvN=tvArr[N_ROWS-1];
  float cv0=data[j*3], cvN=data[(size_t)(N_ROWS-1)*600 + j*3];
  const double Nd = (double)N_ROWS;
  double n = S_b + 1e-8;
  double tmean=S_tb/n, cmean=S_cb/n;
  double cov=(S_tcb - tmean*S_cb - cmean*S_tb + tmean*cmean*S_b)/n;
  double t2=S_ttb - 2.0*tmean*S_tb + tmean*tmean*S_b;
  double c2=S_ccb - 2.0*cmean*S_cb + cmean*cmean*S_b;
  double tstd=sqrt(t2/n + 1e-8), cstd=sqrt(c2/n + 1e-8);
  double corr = cov/(tstd*cstd + 1e-8);
  double mi = -0.5*log(1.0 - fmin(corr*corr, 0.99) + 1e-8);
  float ovn = fminf(tmax,cmax) - fmaxf(tmin,cmin);
  float ovd = fmaxf(tmax-tmin, cmax-cmin) + 1e-8f;
  float overlap = fmaxf(0.f, ovn/ovd);
  double M = Nd - 1.0;
  double Sa=S_t-(double)tv0, Saa=S_tt-(double)tv0*(double)tv0;
  double Sb2=S_c-(double)cvN, Sbb=S_cc-(double)cvN*(double)cvN;
  double lnum = L - Sa*Sb2/M;
  double lden2 = (Saa - Sa*Sa/M)*(Sbb - Sb2*Sb2/M);
  double lag = (lden2 > 0.0) ? lnum/sqrt(lden2) : 0.0;
  double Sa2=S_t-(double)tvN, Saa2=S_tt-(double)tvN*(double)tvN;
  double Sc2=S_c-(double)cv0, Scc2=S_cc-(double)cv0*(double)cv0;
  double rnum = R - Sa2*Sc2/M;
  double rden2 = (Saa2 - Sa2*Sa2/M)*(Scc2 - Sc2*Sc2/M);
  double rev = (rden2 > 0.0) ? rnum/sqrt(rden2) : 0.0;
  double var_t = S_tt/Nd - (S_t/Nd)*(S_t/Nd);
  double var_c = S_cc/Nd - (S_c/Nd)*(S_c/Nd);
  double coef = corr*sqrt(var_t)/(sqrt(var_c) + 1e-8);
  double covf = S_tc/Nd - (S_t/Nd)*(S_c/Nd);
  double var_res = var_t + coef*coef*var_c - 2.0*coef*covf;
  double var_ratio = var_res/(var_t + 1e-8);
  double t_int = S_ti/(S_ci + 1e-8);
  double t_no  = (S_t - S_ti)/((Nd - S_ci) + 1e-8);
  double effect = fabs(t_int - t_no);
  const double m_ = (Nd-1.0)*0.5;
  double rank_corr = (S_rr - Nd*m_*m_) / (Nd*(Nd*Nd-1.0)/12.0);
  float pf[11];
  pf[0]=(float)corr; pf[1]=(float)fabs(corr); pf[2]=(float)(corr*corr); pf[3]=(float)mi;
  pf[4]=overlap; pf[5]=(float)effect; pf[6]=(float)rank_corr;
  pf[7]=(float)((corr>0.0)-(corr<0.0)); pf[8]=(float)lag; pf[9]=(float)rev; pf[10]=(float)var_ratio;
  if (j == tg){
    #pragma unroll
    for (int q=0;q<11;q++) pf[q]=0.f;
  }
  // --- MLP head ---
  const float* nej = ne + (size_t)j*NH;
  float h = b1[t];
  for (int e=0;e<NH;e++) h += te[e]*W1[e*NH + t];
  for (int e=0;e<NH;e++) h += nej[e]*W1[(NH+e)*NH + t];
  #pragma unroll
  for (int f=0;f<11;f++) h += 10.f*pf[f]*W1[(2*NH+f)*NH + t];
  h = gelu_t(h);
  __shared__ float redW[2];
  __shared__ float hnS[NH];
  __shared__ float h2S[64];
  float v = h;
  for (int off=32; off; off>>=1) v += __shfl_down(v, off);
  if ((t&63)==0) redW[t>>6]=v;
  __syncthreads();
  float mu = (redW[0]+redW[1])*(1.f/128.f);
  __syncthreads();
  float d = h - mu;
  v = d*d;
  for (int off=32; off; off>>=1) v += __shfl_down(v, off);
  if ((t&63)==0) redW[t>>6]=v;
  __syncthreads();
  float var = (redW[0]+redW[1])*(1.f/128.f);
  float hn = d/sqrtf(var + 1e-5f)*lns[t] + lno[t];
  hnS[t] = hn;
  __syncthreads();
  if (t < 64){
    float h2 = b2[t];
    for (int o=0;o<NH;o++) h2 += hnS[o]*W2[o*64 + t];
    h2S[t] = gelu_t(h2);
  }
  __syncthreads();
  float netv = 0.f, scv = 0.f;
  if (t < 64){
    float v2 = h2S[t]*W3[t];
    for (int off=32; off; off>>=1) v2 += __shfl_down(v2, off);
    if (t==0) netv = v2 + b3[0];
  }
  if (t < 32){
    float q = bq[t], k = bk[t] + bpair[t];
    for (int e=0;e<NH;e++){ q += te[e]*Wq[e*NKD + t]; k += nej[e]*Wk[e*NKD + t]; }
    #pragma unroll
    for (int f=0;f<11;f++) k += pf[f]*Wpair[f*NKD + t];
    float sc = k*q;
    for (int off=16; off; off>>=1) sc += __shfl_down(sc, off, 32);
    if (t==0) scv = sc/sqrtf(32.f);
  }
  if (t == 0){
    float direct = pf[0]*Wd[0] + pf[8]*Wd[1] + pf[10]*Wd[2];
    out[j] = scv + netv + 0.5f*direct;
  }
}

// ---------------- launcher ----------------
extern "C" void kernel_launch(void* const* d_in, const int* in_sizes, int n_in,
                              void* d_out, int out_size, void* d_ws, size_t ws_size,
                              hipStream_t stream) {
  const float* te    = (const float*)d_in[0];
  const float* ne    = (const float*)d_in[1];
  const float* data  = (const float*)d_in[2];
  const float* Wpair = (const float*)d_in[3];
  const float* bpair = (const float*)d_in[4];
  const float* Wq    = (const float*)d_in[5];
  const float* bq    = (const float*)d_in[6];
  const float* Wk    = (const float*)d_in[7];
  const float* bk    = (const float*)d_in[8];
  const float* W1    = (const float*)d_in[9];
  const float* b1    = (const float*)d_in[10];
  const float* lns   = (const float*)d_in[11];
  const float* lno   = (const float*)d_in[12];
  const float* W2    = (const float*)d_in[13];
  const float* b2    = (const float*)d_in[14];
  const float* W3    = (const float*)d_in[15];
  const float* b3    = (const float*)d_in[16];
  const float* Wd    = (const float*)d_in[17];
  const int*   tgt   = (const int*)d_in[18];
  float* out = (float*)d_out;

  char* ws = (char*)d_ws;
  size_t off = 0;
  auto alloc = [&](size_t bytes)->char*{
    char* p = ws + off;
    off = (off + bytes + 255) & ~(size_t)255;
    return p;
  };
  uint16_t*     bktT     = (uint16_t*)    alloc((size_t)NV*N_ROWS*2);
  float*        tvArr    = (float*)       alloc(N_ROWS*4);
  float*        tiArr    = (float*)       alloc(N_ROWS*4);
  float*        trArr    = (float*)       alloc(N_ROWS*4);
  unsigned int* histT    = (unsigned int*)alloc(NBKT*4);
  double*       tvP      = (double*)      alloc(256*4*8);
  double*       tvStats  = (double*)      alloc(4*8);
  float*        colP     = (float*)       alloc((size_t)NV*NB2A*16*4);
  double*       colStats = (double*)      alloc((size_t)NV*16*8);
  if (off > ws_size) return;  // insufficient workspace -> fail visibly

  hipMemsetAsync(histT, 0, NBKT*4, stream);
  k_extract<<<dim3(N_ROWS/256), dim3(256), 0, stream>>>(data, tgt, tvArr, tiArr, histT, tvP);
  k_comb_tv<<<dim3(1), dim3(256), 0, stream>>>(tvP, tvStats);
  k_scan<<<dim3(1), dim3(256), 0, stream>>>(histT);
  k_trank<<<dim3(N_ROWS/256), dim3(256), 0, stream>>>(tvArr, histT, trArr);
  k_main<<<dim3(NB2A), dim3(256), 0, stream>>>(data, tvArr, tiArr, bktT, colP);
  k_comb_cols<<<dim3(NV), dim3(256), 0, stream>>>(colP, colStats);
  k_rank<<<dim3(NV), dim3(512), 0, stream>>>(bktT, trArr, colStats);
  k_head<<<dim3(NV), dim3(128), 0, stream>>>(te, ne, data, Wpair, bpair, Wq, bq, Wk, bk,
                                             W1, b1, lns, lno, W2, b2, W3, b3, Wd, tgt,
                                             colStats, tvStats, tvArr, out);
}

// Round 4
// 410.626 us; speedup vs baseline: 1.1295x; 1.0211x over previous
//
#include <hip/hip_runtime.h>
#include <stdint.h>

#define N_ROWS 65536
#define NV 200
#define NH 128
#define NKD 32
#define NBKT 32768
#define ROWS_B 32
#define NB2A (N_ROWS/ROWS_B)   // 2048 blocks in k_main; 32 rows each

__device__ __forceinline__ uint32_t fkey(float x){
  uint32_t u = __float_as_uint(x);
  return (u & 0x80000000u) ? ~u : (u | 0x80000000u);
}

// ---------------- K0: extract tv/ti, tv histogram, tv partial stats ----------------
__global__ __launch_bounds__(256) void k_extract(
    const float* __restrict__ data, const int* __restrict__ tgt,
    float* __restrict__ tvArr, float* __restrict__ tiArr,
    unsigned int* __restrict__ histT, double* __restrict__ tvP){
  int i = blockIdx.x*256 + threadIdx.x;   // grid exactly N_ROWS threads
  int tg = *tgt;
  float v  = data[(size_t)i*600 + tg*3 + 0];
  float ti = data[(size_t)i*600 + tg*3 + 1];
  tvArr[i] = v; tiArr[i] = ti;
  atomicAdd(&histT[fkey(v)>>17], 1u);
  double s = (double)v, ss = (double)v*(double)v;
  float mn = v, mx = v;
  for (int off=32; off; off>>=1){
    s  += __shfl_down(s,  off);
    ss += __shfl_down(ss, off);
    mn = fminf(mn, __shfl_down(mn, off));
    mx = fmaxf(mx, __shfl_down(mx, off));
  }
  __shared__ double sd[4][4];
  int w = threadIdx.x >> 6;
  if ((threadIdx.x & 63) == 0){ sd[w][0]=s; sd[w][1]=ss; sd[w][2]=mn; sd[w][3]=mx; }
  __syncthreads();
  if (threadIdx.x == 0){
    double S=0, SS=0, MN=sd[0][2], MX=sd[0][3];
    for (int q=0;q<4;q++){ S+=sd[q][0]; SS+=sd[q][1]; MN=fmin(MN,sd[q][2]); MX=fmax(MX,sd[q][3]); }
    double* p = tvP + (size_t)blockIdx.x*4;
    p[0]=S; p[1]=SS; p[2]=MN; p[3]=MX;
  }
}

// ---------------- K0b: combine 256 tv partials ----------------
__global__ __launch_bounds__(256) void k_comb_tv(const double* __restrict__ tvP,
                                                 double* __restrict__ tvStats){
  int t = threadIdx.x;
  double s = tvP[t*4+0], ss = tvP[t*4+1], mn = tvP[t*4+2], mx = tvP[t*4+3];
  for (int off=32; off; off>>=1){
    s  += __shfl_down(s,  off);
    ss += __shfl_down(ss, off);
    mn = fmin(mn, __shfl_down(mn, off));
    mx = fmax(mx, __shfl_down(mx, off));
  }
  __shared__ double sd[4][4];
  int w = t >> 6;
  if ((t & 63) == 0){ sd[w][0]=s; sd[w][1]=ss; sd[w][2]=mn; sd[w][3]=mx; }
  __syncthreads();
  if (t == 0){
    double S=0, SS=0, MN=sd[0][2], MX=sd[0][3];
    for (int q=0;q<4;q++){ S+=sd[q][0]; SS+=sd[q][1]; MN=fmin(MN,sd[q][2]); MX=fmax(MX,sd[q][3]); }
    tvStats[0]=S; tvStats[1]=SS; tvStats[2]=MN; tvStats[3]=MX;
  }
}

// ---------------- K1s: scan tv histogram -> midrank LUT (LDS, padded, conflict-free) ----------------
__global__ __launch_bounds__(256) void k_scan(unsigned int* __restrict__ histT){
  __shared__ unsigned int h[256*129];   // 132,096 B; chunk c at h[c*129 .. +127]
  __shared__ unsigned int aux[256];
  int t = threadIdx.x;
  for (int idx=t; idx<NBKT; idx+=256) h[(idx>>7)*129 + (idx&127)] = histT[idx];
  __syncthreads();
  unsigned int s = 0;
  #pragma unroll 8
  for (int k=0;k<128;k++) s += h[t*129+k];      // bank = (t+k)%32 : conflict-free
  aux[t] = s; __syncthreads();
  for (int off=1; off<256; off<<=1){
    unsigned int v = (t>=off) ? aux[t-off] : 0u;
    __syncthreads();
    aux[t] += v;
    __syncthreads();
  }
  unsigned int run = aux[t] - s;       // exclusive prefix of chunk
  #pragma unroll 8
  for (int k=0;k<128;k++){
    unsigned int c = h[t*129+k];
    h[t*129+k] = __float_as_uint((float)run + 0.5f*((float)c - 1.f));
    run += c;
  }
  __syncthreads();
  for (int idx=t; idx<NBKT; idx+=256) histT[idx] = h[(idx>>7)*129 + (idx&127)];
}

// ---------------- K1b: tv midranks ----------------
__global__ __launch_bounds__(256) void k_trank(const float* __restrict__ tvArr,
                                               const unsigned int* __restrict__ histT,
                                               float* __restrict__ trArr){
  int i = blockIdx.x*256 + threadIdx.x;
  trArr[i] = __uint_as_float(histT[fkey(tvArr[i])>>17]);
}

// ---------------- K2a: main pass — per-column sums + min/max + bktT transpose ----------------
// 2048 blocks x 32 rows. Register-staged loads: all 19 float4 in flight, then decode.
__global__ __launch_bounds__(256, 4) void k_main(
    const float* __restrict__ data, const float* __restrict__ tvArr,
    const float* __restrict__ tiArr, uint16_t* __restrict__ bktT,
    float* __restrict__ colP){
  __shared__ float   cvS[ROWS_B][201];
  __shared__ uint8_t ciS[ROWS_B][204];
  __shared__ float   tvS[ROWS_B+2];
  __shared__ float   tiS[ROWS_B];
  int t = threadIdx.x, blk = blockIdx.x;
  int i0 = blk*ROWS_B;

  // ---- phase A1: issue ALL loads into registers (MLP: 19 in flight) ----
  const float4* rb = (const float4*)(data + (size_t)i0*600);
  float4 vals[19];
  #pragma unroll
  for (int k=0;k<18;k++) vals[k] = rb[t + k*256];
  if (t < 192) vals[18] = rb[t + 18*256];      // 4800 total float4s
  if (t < ROWS_B+2){ int i = i0 - 1 + t; tvS[t] = (i>=0 && i<N_ROWS) ? tvArr[i] : 0.f; }
  else if (t >= 64 && t < 64+ROWS_B){ tiS[t-64] = tiArr[i0 + (t-64)]; }

  // ---- phase A2: decode into LDS ----
  #pragma unroll
  for (int k=0;k<19;k++){
    int f = t + k*256;
    if (k < 18 || t < 192){
      float4 v = vals[k];
      int r  = f/150;
      int e4 = f - r*150;
      int m  = e4 % 3;
      int c0 = (4*e4)/3;
      if (m==0){ cvS[r][c0]=v.x; ciS[r][c0]=(uint8_t)(v.y>0.5f); cvS[r][c0+1]=v.w; }
      else if (m==1){ ciS[r][c0]=(uint8_t)(v.x>0.5f); cvS[r][c0+1]=v.z; ciS[r][c0+1]=(uint8_t)(v.w>0.5f); }
      else { cvS[r][c0+1]=v.y; ciS[r][c0+1]=(uint8_t)(v.z>0.5f); }
    }
  }
  __syncthreads();

  // ---- phase B: per-column accumulate (thread t <-> column t) ----
  if (t < NV){
    float facc[13];
    #pragma unroll
    for (int s=0;s<13;s++) facc[s]=0.f;
    float cmin = 3.4e38f, cmax = -3.4e38f;
    for (int r=0;r<ROWS_B;r++){
      float cv = cvS[r][t];
      float ci = (float)ciS[r][t];
      float tv = tvS[r+1], tvm = tvS[r], tvp = tvS[r+2];
      float ti = tiS[r];
      float b  = (1.f-ti)*(1.f-ci);
      facc[0]+=cv;        facc[1]+=cv*cv;     facc[2]+=tv*cv;
      facc[3]+=ci;        facc[4]+=tv*ci;
      facc[5]+=b;         facc[6]+=tv*b;      facc[7]+=cv*b;
      facc[8]+=tv*cv*b;   facc[9]+=tv*tv*b;   facc[10]+=cv*cv*b;
      facc[11]+=tvp*cv;   facc[12]+=tvm*cv;
      cmin = fminf(cmin, cv); cmax = fmaxf(cmax, cv);
    }
    float* dst = colP + ((size_t)t*NB2A + blk)*16;
    #pragma unroll
    for (int s=0;s<13;s++) dst[s] = facc[s];
    dst[13]=cmin; dst[14]=cmax;
  }

  // ---- phase C: transposed bucket write ----
  {
    int r = t & 31, cb = t >> 5;
    for (int cc=cb; cc<NV; cc+=8){
      float cv = cvS[r][cc];
      bktT[(size_t)cc*N_ROWS + i0 + r] = (uint16_t)(fkey(cv)>>17);
    }
  }
}

// ---------------- K2c: combine per-column partials ----------------
__global__ __launch_bounds__(256) void k_comb_cols(const float* __restrict__ colP,
                                                   double* __restrict__ colStats){
  int j = blockIdx.x, t = threadIdx.x;
  double a[13];
  #pragma unroll
  for (int s=0;s<13;s++) a[s]=0.0;
  float mn = 3.4e38f, mx = -3.4e38f;
  for (int b=t; b<NB2A; b+=256){
    const float* p = colP + ((size_t)j*NB2A + b)*16;
    #pragma unroll
    for (int s=0;s<13;s++) a[s] += (double)p[s];
    mn = fminf(mn, p[13]); mx = fmaxf(mx, p[14]);
  }
  for (int off=32; off; off>>=1){
    #pragma unroll
    for (int s=0;s<13;s++) a[s] += __shfl_down(a[s], off);
    mn = fminf(mn, __shfl_down(mn, off));
    mx = fmaxf(mx, __shfl_down(mx, off));
  }
  __shared__ double sd[4][15];
  int w = t >> 6;
  if ((t & 63) == 0){
    #pragma unroll
    for (int s=0;s<13;s++) sd[w][s]=a[s];
    sd[w][13]=(double)mn; sd[w][14]=(double)mx;
  }
  __syncthreads();
  if (t == 0){
    double* d = colStats + (size_t)j*16;
    #pragma unroll
    for (int s=0;s<13;s++) d[s] = sd[0][s]+sd[1][s]+sd[2][s]+sd[3][s];
    double MN=sd[0][13], MX=sd[0][14];
    for (int q=1;q<4;q++){ MN=fmin(MN,sd[q][13]); MX=fmax(MX,sd[q][14]); }
    d[13]=MN; d[14]=MX;
  }
}

// ---------------- K2b: per-column Spearman numerator via padded LDS histogram ----------------
__global__ __launch_bounds__(512, 1) void k_rank(const uint16_t* __restrict__ bktT,
                                                 const float* __restrict__ trArr,
                                                 double* __restrict__ colStats){
  __shared__ unsigned int h[512*65];   // 133,120 B; bucket b at h[(b>>6)*65 + (b&63)]
  __shared__ unsigned int aux[512];
  __shared__ double daux[8];
  int t = threadIdx.x, j = blockIdx.x;
  const uint16_t* col = bktT + (size_t)j*N_ROWS;
  for (int idx=t; idx<512*65; idx+=512) h[idx]=0u;
  __syncthreads();
  for (int k=0;k<N_ROWS/512;k++){
    int b = (int)col[t + k*512];
    atomicAdd(&h[(b>>6)*65 + (b&63)], 1u);
  }
  __syncthreads();
  unsigned int s = 0;
  #pragma unroll 8
  for (int k=0;k<64;k++) s += h[t*65+k];        // bank = (t+k)%32 : conflict-free
  aux[t]=s; __syncthreads();
  for (int off=1; off<512; off<<=1){
    unsigned int v = (t>=off) ? aux[t-off] : 0u;
    __syncthreads();
    aux[t] += v;
    __syncthreads();
  }
  unsigned int run = aux[t] - s;
  #pragma unroll 8
  for (int k=0;k<64;k++){
    unsigned int c = h[t*65+k];
    h[t*65+k] = __float_as_uint((float)run + 0.5f*((float)c - 1.f));
    run += c;
  }
  __syncthreads();
  double srr = 0.0;
  for (int k=0;k<N_ROWS/512;k++){
    int i = t + k*512;
    int b = (int)col[i];
    srr += (double)trArr[i] * (double)__uint_as_float(h[(b>>6)*65 + (b&63)]);
  }
  for (int off=32; off; off>>=1) srr += __shfl_down(srr, off);
  if ((t&63)==0) daux[t>>6] = srr;
  __syncthreads();
  if (t==0){
    double s8=0;
    for (int q=0;q<8;q++) s8 += daux[q];
    colStats[(size_t)j*16 + 15] = s8;
  }
}

// ---------------- K5: features + attention/MLP head ----------------
__device__ __forceinline__ float gelu_t(float x){
  float x3 = x*x*x;
  return 0.5f*x*(1.f + tanhf(0.7978845608f*(x + 0.044715f*x3)));
}

__global__ __launch_bounds__(128) void k_head(
    const float* __restrict__ te, const float* __restrict__ ne, const float* __restrict__ data,
    const float* __restrict__ Wpair, const float* __restrict__ bpair,
    const float* __restrict__ Wq, const float* __restrict__ bq,
    const float* __restrict__ Wk, const float* __restrict__ bk,
    const float* __restrict__ W1, const float* __restrict__ b1,
    const float* __restrict__ lns, const float* __restrict__ lno,
    const float* __restrict__ W2, const float* __restrict__ b2,
    const float* __restrict__ W3, const float* __restrict__ b3,
    const float* __restrict__ Wd, const int* __restrict__ tgt,
    const double* __restrict__ colStats, const double* __restrict__ tvStats,
    const float* __restrict__ tvArr, float* __restrict__ out){
  int j = blockIdx.x, t = threadIdx.x;
  int tg = *tgt;
  const double* cs = colStats + (size_t)j*16;
  double S_c=cs[0], S_cc=cs[1], S_tc=cs[2], S_ci=cs[3], S_ti=cs[4], S_b=cs[5],
         S_tb=cs[6], S_cb=cs[7], S_tcb=cs[8], S_ttb=cs[9], S_ccb=cs[10], L=cs[11], R=cs[12];
  float cmin=(float)cs[13], cmax=(float)cs[14];
  double S_rr=cs[15];
  double S_t=tvStats[0], S_tt=tvStats[1];
  float tmin=(float)tvStats[2], tmax=(float)tvStats[3];
  float tv0=tvArr[0], tvN=tvArr[N_ROWS-1];
  float cv0=data[j*3], cvN=data[(size_t)(N_ROWS-1)*600 + j*3];
  const double Nd = (double)N_ROWS;
  double n = S_b + 1e-8;
  double tmean=S_tb/n, cmean=S_cb/n;
  double cov=(S_tcb - tmean*S_cb - cmean*S_tb + tmean*cmean*S_b)/n;
  double t2=S_ttb - 2.0*tmean*S_tb + tmean*tmean*S_b;
  double c2=S_ccb - 2.0*cmean*S_cb + cmean*cmean*S_b;
  double tstd=sqrt(t2/n + 1e-8), cstd=sqrt(c2/n + 1e-8);
  double corr = cov/(tstd*cstd + 1e-8);
  double mi = -0.5*log(1.0 - fmin(corr*corr, 0.99) + 1e-8);
  float ovn = fminf(tmax,cmax) - fmaxf(tmin,cmin);
  float ovd = fmaxf(tmax-tmin, cmax-cmin) + 1e-8f;
  float overlap = fmaxf(0.f, ovn/ovd);
  double M = Nd - 1.0;
  double Sa=S_t-(double)tv0, Saa=S_tt-(double)tv0*(double)tv0;
  double Sb2=S_c-(double)cvN, Sbb=S_cc-(double)cvN*(double)cvN;
  double lnum = L - Sa*Sb2/M;
  double lden2 = (Saa - Sa*Sa/M)*(Sbb - Sb2*Sb2/M);
  double lag = (lden2 > 0.0) ? lnum/sqrt(lden2) : 0.0;
  double Sa2=S_t-(double)tvN, Saa2=S_tt-(double)tvN*(double)tvN;
  double Sc2=S_c-(double)cv0, Scc2=S_cc-(double)cv0*(double)cv0;
  double rnum = R - Sa2*Sc2/M;
  double rden2 = (Saa2 - Sa2*Sa2/M)*(Scc2 - Sc2*Sc2/M);
  double rev = (rden2 > 0.0) ? rnum/sqrt(rden2) : 0.0;
  double var_t = S_tt/Nd - (S_t/Nd)*(S_t/Nd);
  double var_c = S_cc/Nd - (S_c/Nd)*(S_c/Nd);
  double coef = corr*sqrt(var_t)/(sqrt(var_c) + 1e-8);
  double covf = S_tc/Nd - (S_t/Nd)*(S_c/Nd);
  double var_res = var_t + coef*coef*var_c - 2.0*coef*covf;
  double var_ratio = var_res/(var_t + 1e-8);
  double t_int = S_ti/(S_ci + 1e-8);
  double t_no  = (S_t - S_ti)/((Nd - S_ci) + 1e-8);
  double effect = fabs(t_int - t_no);
  const double m_ = (Nd-1.0)*0.5;
  double rank_corr = (S_rr - Nd*m_*m_) / (Nd*(Nd*Nd-1.0)/12.0);
  float pf[11];
  pf[0]=(float)corr; pf[1]=(float)fabs(corr); pf[2]=(float)(corr*corr); pf[3]=(float)mi;
  pf[4]=overlap; pf[5]=(float)effect; pf[6]=(float)rank_corr;
  pf[7]=(float)((corr>0.0)-(corr<0.0)); pf[8]=(float)lag; pf[9]=(float)rev; pf[10]=(float)var_ratio;
  if (j == tg){
    #pragma unroll
    for (int q=0;q<11;q++) pf[q]=0.f;
  }
  // --- MLP head ---
  const float* nej = ne + (size_t)j*NH;
  float h = b1[t];
  for (int e=0;e<NH;e++) h += te[e]*W1[e*NH + t];
  for (int e=0;e<NH;e++) h += nej[e]*W1[(NH+e)*NH + t];
  #pragma unroll
  for (int f=0;f<11;f++) h += 10.f*pf[f]*W1[(2*NH+f)*NH + t];
  h = gelu_t(h);
  __shared__ float redW[2];
  __shared__ float hnS[NH];
  __shared__ float h2S[64];
  float v = h;
  for (int off=32; off; off>>=1) v += __shfl_down(v, off);
  if ((t&63)==0) redW[t>>6]=v;
  __syncthreads();
  float mu = (redW[0]+redW[1])*(1.f/128.f);
  __syncthreads();
  float d = h - mu;
  v = d*d;
  for (int off=32; off; off>>=1) v += __shfl_down(v, off);
  if ((t&63)==0) redW[t>>6]=v;
  __syncthreads();
  float var = (redW[0]+redW[1])*(1.f/128.f);
  float hn = d/sqrtf(var + 1e-5f)*lns[t] + lno[t];
  hnS[t] = hn;
  __syncthreads();
  if (t < 64){
    float h2 = b2[t];
    for (int o=0;o<NH;o++) h2 += hnS[o]*W2[o*64 + t];
    h2S[t] = gelu_t(h2);
  }
  __syncthreads();
  float netv = 0.f, scv = 0.f;
  if (t < 64){
    float v2 = h2S[t]*W3[t];
    for (int off=32; off; off>>=1) v2 += __shfl_down(v2, off);
    if (t==0) netv = v2 + b3[0];
  }
  if (t < 32){
    float q = bq[t], k = bk[t] + bpair[t];
    for (int e=0;e<NH;e++){ q += te[e]*Wq[e*NKD + t]; k += nej[e]*Wk[e*NKD + t]; }
    #pragma unroll
    for (int f=0;f<11;f++) k += pf[f]*Wpair[f*NKD + t];
    float sc = k*q;
    for (int off=16; off; off>>=1) sc += __shfl_down(sc, off, 32);
    if (t==0) scv = sc/sqrtf(32.f);
  }
  if (t == 0){
    float direct = pf[0]*Wd[0] + pf[8]*Wd[1] + pf[10]*Wd[2];
    out[j] = scv + netv + 0.5f*direct;
  }
}

// ---------------- launcher ----------------
extern "C" void kernel_launch(void* const* d_in, const int* in_sizes, int n_in,
                              void* d_out, int out_size, void* d_ws, size_t ws_size,
                              hipStream_t stream) {
  const float* te    = (const float*)d_in[0];
  const float* ne    = (const float*)d_in[1];
  const float* data  = (const float*)d_in[2];
  const float* Wpair = (const float*)d_in[3];
  const float* bpair = (const float*)d_in[4];
  const float* Wq    = (const float*)d_in[5];
  const float* bq    = (const float*)d_in[6];
  const float* Wk    = (const float*)d_in[7];
  const float* bk    = (const float*)d_in[8];
  const float* W1    = (const float*)d_in[9];
  const float* b1    = (const float*)d_in[10];
  const float* lns   = (const float*)d_in[11];
  const float* lno   = (const float*)d_in[12];
  const float* W2    = (const float*)d_in[13];
  const float* b2    = (const float*)d_in[14];
  const float* W3    = (const float*)d_in[15];
  const float* b3    = (const float*)d_in[16];
  const float* Wd    = (const float*)d_in[17];
  const int*   tgt   = (const int*)d_in[18];
  float* out = (float*)d_out;

  char* ws = (char*)d_ws;
  size_t off = 0;
  auto alloc = [&](size_t bytes)->char*{
    char* p = ws + off;
    off = (off + bytes + 255) & ~(size_t)255;
    return p;
  };
  uint16_t*     bktT     = (uint16_t*)    alloc((size_t)NV*N_ROWS*2);
  float*        tvArr    = (float*)       alloc(N_ROWS*4);
  float*        tiArr    = (float*)       alloc(N_ROWS*4);
  float*        trArr    = (float*)       alloc(N_ROWS*4);
  unsigned int* histT    = (unsigned int*)alloc(NBKT*4);
  double*       tvP      = (double*)      alloc(256*4*8);
  double*       tvStats  = (double*)      alloc(4*8);
  float*        colP     = (float*)       alloc((size_t)NV*NB2A*16*4);
  double*       colStats = (double*)      alloc((size_t)NV*16*8);
  if (off > ws_size) return;  // insufficient workspace -> fail visibly

  hipMemsetAsync(histT, 0, NBKT*4, stream);
  k_extract<<<dim3(N_ROWS/256), dim3(256), 0, stream>>>(data, tgt, tvArr, tiArr, histT, tvP);
  k_comb_tv<<<dim3(1), dim3(256), 0, stream>>>(tvP, tvStats);
  k_scan<<<dim3(1), dim3(256), 0, stream>>>(histT);
  k_trank<<<dim3(N_ROWS/256), dim3(256), 0, stream>>>(tvArr, histT, trArr);
  k_main<<<dim3(NB2A), dim3(256), 0, stream>>>(data, tvArr, tiArr, bktT, colP);
  k_comb_cols<<<dim3(NV), dim3(256), 0, stream>>>(colP, colStats);
  k_rank<<<dim3(NV), dim3(512), 0, stream>>>(bktT, trArr, colStats);
  k_head<<<dim3(NV), dim3(128), 0, stream>>>(te, ne, data, Wpair, bpair, Wq, bq, Wk, bk,
                                             W1, b1, lns, lno, W2, b2, W3, b3, Wd, tgt,
                                             colStats, tvStats, tvArr, out);
}